// Round 6
// baseline (540.392 us; speedup 1.0000x reference)
//
#include <hip/hip_runtime.h>
#include <hip/hip_bf16.h>

#define N_NODES 50000
#define N_EDGES 1600000
#define HEADS 8
#define HD 32
#define FIN 256
#define HID 256

typedef unsigned short u16;
typedef unsigned int u32;
typedef unsigned char u8;

typedef short s8v __attribute__((ext_vector_type(8)));   // 8 bf16 (4 VGPRs)
typedef float f4v __attribute__((ext_vector_type(4)));   // 4 fp32 acc
typedef float f2v __attribute__((ext_vector_type(2)));

__device__ __forceinline__ float bf2f(u16 v) {
  union { u32 u; float f; } c; c.u = ((u32)v) << 16; return c.f;
}
__device__ __forceinline__ u16 f2bf(float f) {
  union { u32 u; float f; } c; c.f = f;
  u32 u = c.u;
  return (u16)((u + 0x7FFFu + ((u >> 16) & 1u)) >> 16);  // RNE
}
__device__ __forceinline__ u32 pk2(float lo, float hi) {
  return (u32)f2bf(lo) | ((u32)f2bf(hi) << 16);
}

// ---------------- W transpose prep: Wt_g[h*32+d][k] bf16 --------------------
__global__ __launch_bounds__(256) void k_wprep(const float* __restrict__ W,
                                               u16* __restrict__ Wt_g) {
  int idx = blockIdx.x * 256 + threadIdx.x;   // 16384 threads, one float4 each
  int d4 = idx & 7;                            // 4-d group
  int hk = idx >> 3;                           // h*256 + k
  int h = hk >> 8, k = hk & 255;
  float4 w = *(const float4*)&W[hk * 32 + d4 * 4];
  int colb = h * 32 + d4 * 4;
  Wt_g[(colb + 0) * 256 + k] = f2bf(w.x);
  Wt_g[(colb + 1) * 256 + k] = f2bf(w.y);
  Wt_g[(colb + 2) * 256 + k] = f2bf(w.z);
  Wt_g[(colb + 3) * 256 + k] = f2bf(w.w);
}

// ---------------- MFMA GEMM + fused attn projections ------------------------
__global__ __launch_bounds__(256) void k_gemm(
    const float* __restrict__ X, const u16* __restrict__ Wt_g,
    const float* __restrict__ bw, const float* __restrict__ A,
    u16* __restrict__ Hb, float* __restrict__ si, float* __restrict__ sj) {
  __shared__ __align__(16) u16 Xs[128 * 40];  // [row][k] stride 40
  __shared__ __align__(16) u16 Wt[128 * 40];  // [col][k] stride 40

  const int t = threadIdx.x;
  const int m0 = (blockIdx.x >> 1) * 128;
  const int n0 = (blockIdx.x & 1) * 128;
  const int w = t >> 6;
  const int lane = t & 63;
  const int l15 = lane & 15;
  const int quad = lane >> 4;
  const int wm = (w >> 1) * 64;
  const int wn = (w & 1) * 64;

  f4v acc[4][4];
#pragma unroll
  for (int i = 0; i < 4; i++)
#pragma unroll
    for (int j = 0; j < 4; j++) acc[i][j] = (f4v){0.f, 0.f, 0.f, 0.f};

  const int nl = t & 127;          // local col
  const int half = t >> 7;         // k half: 16 k's

  for (int k0 = 0; k0 < FIN; k0 += 32) {
    // stage X tile: 128 rows x 32 k (fp32 -> bf16)
#pragma unroll
    for (int p = 0; p < 4; p++) {
      int row = p * 32 + (t >> 3);
      int f4 = t & 7;
      int node = m0 + row;
      float4 xv = make_float4(0.f, 0.f, 0.f, 0.f);
      if (node < N_NODES) xv = *(const float4*)&X[node * FIN + k0 + f4 * 4];
      u32* dst = (u32*)&Xs[row * 40 + f4 * 4];
      dst[0] = pk2(xv.x, xv.y);
      dst[1] = pk2(xv.z, xv.w);
    }
    // stage W tile from pre-transposed bf16: 2 x 16B loads per thread
    {
      const u16* wp = Wt_g + (n0 + nl) * 256 + k0 + half * 16;
      *(s8v*)&Wt[nl * 40 + half * 16]     = *(const s8v*)wp;
      *(s8v*)&Wt[nl * 40 + half * 16 + 8] = *(const s8v*)(wp + 8);
    }
    __syncthreads();
    s8v af[4], bf[4];
#pragma unroll
    for (int mi = 0; mi < 4; mi++)
      af[mi] = *(const s8v*)&Xs[(wm + mi * 16 + l15) * 40 + quad * 8];
#pragma unroll
    for (int ni = 0; ni < 4; ni++)
      bf[ni] = *(const s8v*)&Wt[(wn + ni * 16 + l15) * 40 + quad * 8];
#pragma unroll
    for (int mi = 0; mi < 4; mi++)
#pragma unroll
      for (int ni = 0; ni < 4; ni++)
        acc[mi][ni] = __builtin_amdgcn_mfma_f32_16x16x32_bf16(af[mi], bf[ni], acc[mi][ni], 0, 0, 0);
    __syncthreads();
  }

  // epilogue: bias, store bf16 H, fused si/sj
  const int head0 = (n0 + wn) >> 5;
  const int head1 = head0 + 1;
  float c1a0 = A[head0 * 64 + l15],      c1a1 = A[head0 * 64 + 16 + l15];
  float c2a0 = A[head0 * 64 + 32 + l15], c2a1 = A[head0 * 64 + 48 + l15];
  float c1b0 = A[head1 * 64 + l15],      c1b1 = A[head1 * 64 + 16 + l15];
  float c2b0 = A[head1 * 64 + 32 + l15], c2b1 = A[head1 * 64 + 48 + l15];

#pragma unroll
  for (int mi = 0; mi < 4; mi++) {
#pragma unroll
    for (int ni = 0; ni < 4; ni++) {
      float b = bw[n0 + wn + ni * 16 + l15];
#pragma unroll
      for (int r = 0; r < 4; r++) acc[mi][ni][r] += b;
    }
    const int rbase = m0 + wm + mi * 16 + quad * 4;
#pragma unroll
    for (int r = 0; r < 4; r++) {
      int node = rbase + r;
      if (node < N_NODES) {
#pragma unroll
        for (int ni = 0; ni < 4; ni++) {
          int col = n0 + wn + ni * 16 + l15;
          Hb[node * HID + col] = f2bf(acc[mi][ni][r]);
        }
      }
    }
    float s1a[4], s2a[4], s1b[4], s2b[4];
#pragma unroll
    for (int r = 0; r < 4; r++) {
      s1a[r] = acc[mi][0][r] * c1a0 + acc[mi][1][r] * c1a1;
      s2a[r] = acc[mi][0][r] * c2a0 + acc[mi][1][r] * c2a1;
      s1b[r] = acc[mi][2][r] * c1b0 + acc[mi][3][r] * c1b1;
      s2b[r] = acc[mi][2][r] * c2b0 + acc[mi][3][r] * c2b1;
    }
#pragma unroll
    for (int off = 1; off <= 8; off <<= 1) {
#pragma unroll
      for (int r = 0; r < 4; r++) {
        s1a[r] += __shfl_xor(s1a[r], off);
        s2a[r] += __shfl_xor(s2a[r], off);
        s1b[r] += __shfl_xor(s1b[r], off);
        s2b[r] += __shfl_xor(s2b[r], off);
      }
    }
    if (l15 == 0) {
#pragma unroll
      for (int r = 0; r < 4; r++) {
        int node = rbase + r;
        if (node < N_NODES) {
          si[node * HEADS + head0] = s1a[r];
          sj[node * HEADS + head0] = s2a[r];
          si[node * HEADS + head1] = s1b[r];
          sj[node * HEADS + head1] = s2b[r];
        }
      }
    }
  }
}

// ---------------- bf16 H -> fp8 e4m3 Hq (gather payload) --------------------
__global__ __launch_bounds__(256) void k_cvt(const u16* __restrict__ Hb,
                                             u8* __restrict__ Hq) {
  int idx = blockIdx.x * 256 + threadIdx.x;    // 8 elems per thread
  const u32* p = (const u32*)Hb + (size_t)idx * 4;
  u32 w0 = p[0], w1 = p[1], w2 = p[2], w3 = p[3];
  float f0 = bf2f((u16)w0), f1 = bf2f((u16)(w0 >> 16));
  float f2 = bf2f((u16)w1), f3 = bf2f((u16)(w1 >> 16));
  float f4 = bf2f((u16)w2), f5 = bf2f((u16)(w2 >> 16));
  float f6 = bf2f((u16)w3), f7 = bf2f((u16)(w3 >> 16));
  u32 qa = __builtin_amdgcn_cvt_pk_fp8_f32(f0, f1, 0, false);
  qa = __builtin_amdgcn_cvt_pk_fp8_f32(f2, f3, qa, true);
  u32 qb = __builtin_amdgcn_cvt_pk_fp8_f32(f4, f5, 0, false);
  qb = __builtin_amdgcn_cvt_pk_fp8_f32(f6, f7, qb, true);
  u32* q = (u32*)Hq + (size_t)idx * 2;
  q[0] = qa; q[1] = qb;
}

// ---------------- counting sort of edges by target ----------------
__global__ void k_hist(const int* __restrict__ tgt, int* __restrict__ cnt) {
  int e = blockIdx.x * 256 + threadIdx.x;
  if (e < N_EDGES) atomicAdd(&cnt[tgt[e]], 1);
}

__global__ __launch_bounds__(256) void k_scan1(const int* __restrict__ cnt,
    int* __restrict__ excl, int* __restrict__ bsum) {
  __shared__ int s[256];
  const int t = threadIdx.x;
  const int i = blockIdx.x * 256 + t;
  int v = (i < N_NODES) ? cnt[i] : 0;
  s[t] = v;
  __syncthreads();
  int x = v;
  for (int off = 1; off < 256; off <<= 1) {
    int y = (t >= off) ? s[t - off] : 0;
    __syncthreads();
    x += y;
    s[t] = x;
    __syncthreads();
  }
  if (i < N_NODES) excl[i] = x - v;
  if (t == 255) bsum[blockIdx.x] = x;
}

__global__ __launch_bounds__(256) void k_scan2(const int* __restrict__ bsum,
                                               int* __restrict__ boff) {
  __shared__ int s[256];
  const int t = threadIdx.x;
  int v = (t < 196) ? bsum[t] : 0;
  s[t] = v;
  __syncthreads();
  int x = v;
  for (int off = 1; off < 256; off <<= 1) {
    int y = (t >= off) ? s[t - off] : 0;
    __syncthreads();
    x += y;
    s[t] = x;
    __syncthreads();
  }
  if (t < 196) boff[t] = x - v;
}

__global__ void k_scan3(const int* __restrict__ excl, const int* __restrict__ boff,
                        int* __restrict__ rowptr, int* __restrict__ cursor) {
  int i = blockIdx.x * 256 + threadIdx.x;
  if (i < N_NODES) {
    int v = excl[i] + boff[blockIdx.x];
    rowptr[i] = v;
    cursor[i] = v;
  }
}

__global__ void k_scatter(const int* __restrict__ tgt, const int* __restrict__ src,
                          int* __restrict__ cursor, int* __restrict__ sortedSrc) {
  int e = blockIdx.x * 256 + threadIdx.x;
  if (e < N_EDGES) {
    int tg = tgt[e];
    int pos = atomicAdd(&cursor[tg], 1);
    sortedSrc[pos] = src[e];
  }
}

// ---------------- fused: softmax-agg + skip + ELU + LN + head-mean + Wout + ELU
// Phase A: 32 edges x 8 heads -> exp scores in LDS (padded: exv=0).
// Phase B: thread owns 16 cols (float4 = 16 fp8); es = t>>4 edge slot (16);
//          2 unrolled iters/chunk. Partials reduced via swizzled LDS.
__global__ __launch_bounds__(256) void k_fused(
    const u8* __restrict__ Hq, const u16* __restrict__ Hb,
    const float* __restrict__ si, const float* __restrict__ sj,
    const float* __restrict__ ba, const float* __restrict__ gamma,
    const float* __restrict__ beta, const float* __restrict__ Wout,
    const float* __restrict__ bout, const int* __restrict__ rowptr,
    const int* __restrict__ cnt, const int* __restrict__ sortedSrc,
    float* __restrict__ out) {
  __shared__ float exs[32 * 8];
  __shared__ u32   soff[32];
  __shared__ float sbase[8];
  __shared__ float accs[16][256];   // swizzled: phys j = (j + 2*cg + es) & 15
  __shared__ float dens[16][16];
  __shared__ float lnorm[256];
  __shared__ float meanv[32];

  const int n = blockIdx.x;
  const int t = threadIdx.x;
  const int cg = t & 15;           // col group: cols cg*16 .. cg*16+15
  const int es = t >> 4;           // edge slot 0..15
  const int hh = cg >> 1;          // head of this col group
  const int start = rowptr[n];
  const int deg = cnt[n];
  if (t < 8) sbase[t] = si[n * HEADS + t] + ba[t];
  __syncthreads();

  const int i2c = t >> 3, h8 = t & 7;
  float acc[16];
#pragma unroll
  for (int j = 0; j < 16; j++) acc[j] = 0.f;
  float den = 0.f;
  for (int base = 0; base < deg; base += 32) {
    const int m = min(32, deg - base);
    {
      float exv = 0.f;
      u32 off0 = 0;
      if (i2c < m) {
        int s = sortedSrc[start + base + i2c];
        float e = sbase[h8] + sj[s * HEADS + h8];
        e = (e >= 0.f) ? e : 0.2f * e;
        exv = __expf(e);
        off0 = (u32)s * 256u;
      }
      exs[i2c * 8 + h8] = exv;
      if (h8 == 0) soff[i2c] = off0;
    }
    __syncthreads();
#pragma unroll
    for (int k = 0; k < 2; k++) {
      int i2 = k * 16 + es;
      u32 off = soff[i2];
      float exv = exs[i2 * 8 + hh];
      float4 q4 = *(const float4*)(Hq + off + 16 * cg);
      const u32* qw = (const u32*)&q4;
#pragma unroll
      for (int d = 0; d < 4; d++) {
        f2v lo = __builtin_amdgcn_cvt_pk_f32_fp8(qw[d], false);
        f2v hi = __builtin_amdgcn_cvt_pk_f32_fp8(qw[d], true);
        acc[4 * d + 0] += exv * lo.x;
        acc[4 * d + 1] += exv * lo.y;
        acc[4 * d + 2] += exv * hi.x;
        acc[4 * d + 3] += exv * hi.y;
      }
      den += exv;
    }
    __syncthreads();
  }
#pragma unroll
  for (int j = 0; j < 16; j++)
    accs[es][cg * 16 + ((j + 2 * cg + es) & 15)] = acc[j];
  dens[es][cg] = den;
  __syncthreads();

  const int cgq = t >> 4, jq = t & 15;
  float accT = 0.f, denT = 0.f;
#pragma unroll
  for (int e2 = 0; e2 < 16; e2++) {
    accT += accs[e2][cgq * 16 + ((jq + 2 * cgq + e2) & 15)];
    denT += dens[e2][cgq];
  }
  float hs = bf2f(Hb[n * HID + t]);
  float v = ((deg > 0) ? (accT / denT) : 0.f) + hs;
  v = (v > 0.f) ? v : expm1f(v);
  float sum = v, sq = v * v;
#pragma unroll
  for (int off = 16; off >= 1; off >>= 1) {
    sum += __shfl_xor(sum, off);
    sq  += __shfl_xor(sq, off);
  }
  float mu = sum * (1.f / 32.f);
  float var = sq * (1.f / 32.f) - mu * mu;
  float nv = (v - mu) * rsqrtf(var + 1e-5f) * gamma[t] + beta[t];
  lnorm[t] = nv;
  __syncthreads();
  if (t < 32) {
    float m2 = 0.f;
#pragma unroll
    for (int h2 = 0; h2 < HEADS; h2++) m2 += lnorm[h2 * 32 + t];
    meanv[t] = m2 * 0.125f;
  }
  __syncthreads();
  float y = bout[t];
#pragma unroll
  for (int k = 0; k < 32; k++) y += meanv[k] * Wout[k * HID + t];
  y = (y > 0.f) ? y : expm1f(y);
  out[n * HID + t] = y;
}

extern "C" void kernel_launch(void* const* d_in, const int* in_sizes, int n_in,
                              void* d_out, int out_size, void* d_ws, size_t ws_size,
                              hipStream_t stream) {
  const float* X     = (const float*)d_in[0];
  const int*   EI    = (const int*)d_in[1];
  const float* W     = (const float*)d_in[2];
  const float* bw    = (const float*)d_in[3];
  const float* A     = (const float*)d_in[4];
  const float* ba    = (const float*)d_in[5];
  const float* gamma = (const float*)d_in[6];
  const float* beta  = (const float*)d_in[7];
  const float* Wout  = (const float*)d_in[8];
  const float* bout  = (const float*)d_in[9];
  float* out = (float*)d_out;
  const int* tgt = EI;
  const int* src = EI + N_EDGES;

  char* ws = (char*)d_ws;
  size_t off = 0;
  auto alloc = [&](size_t bytes) -> void* {
    void* p = ws + off;
    off += bytes;
    off = (off + 255) & ~(size_t)255;
    return p;
  };
  u16*   Hb        = (u16*)  alloc((size_t)N_NODES * HID * 2);
  u8*    Hq        = (u8*)   alloc((size_t)N_NODES * HID);
  u16*   Wt_g      = (u16*)  alloc((size_t)HID * FIN * 2);
  float* si        = (float*)alloc((size_t)N_NODES * HEADS * 4);
  float* sj        = (float*)alloc((size_t)N_NODES * HEADS * 4);
  int*   cnt       = (int*)  alloc((size_t)N_NODES * 4);
  int*   excl      = (int*)  alloc((size_t)N_NODES * 4);
  int*   bsum      = (int*)  alloc(256 * 4);
  int*   boff      = (int*)  alloc(256 * 4);
  int*   rowptr    = (int*)  alloc((size_t)N_NODES * 4);
  int*   cursor    = (int*)  alloc((size_t)N_NODES * 4);
  int*   sortedSrc = (int*)  alloc((size_t)N_EDGES * 4);

  hipMemsetAsync(cnt, 0, (size_t)N_NODES * 4, stream);
  k_hist<<<(N_EDGES + 255) / 256, 256, 0, stream>>>(tgt, cnt);
  k_scan1<<<196, 256, 0, stream>>>(cnt, excl, bsum);
  k_scan2<<<1, 256, 0, stream>>>(bsum, boff);
  k_scan3<<<196, 256, 0, stream>>>(excl, boff, rowptr, cursor);
  k_scatter<<<(N_EDGES + 255) / 256, 256, 0, stream>>>(tgt, src, cursor, sortedSrc);
  k_wprep<<<64, 256, 0, stream>>>(W, Wt_g);
  k_gemm<<<((N_NODES + 127) / 128) * 2, 256, 0, stream>>>(X, Wt_g, bw, A, Hb, si, sj);
  k_cvt<<<(N_NODES * HID / 8 + 255) / 256, 256, 0, stream>>>(Hb, Hq);
  k_fused<<<N_NODES, 256, 0, stream>>>(Hq, Hb, si, sj, ba, gamma, beta, Wout, bout,
                                       rowptr, cnt, sortedSrc, out);
}